// Round 1
// baseline (1745.725 us; speedup 1.0000x reference)
//
#include <hip/hip_runtime.h>
#include <hip/hip_fp16.h>
#include <cstdint>
#include <cstddef>

// Problem constants (setup_inputs: B=8,S=2048,D=768,E=8,I=3072,H=1536,top_k=2)
#define TK 16384   // tokens
#define DD 768
#define EE 8
#define II 3072
#define HH 1536

typedef _Float16 half8 __attribute__((ext_vector_type(8)));
typedef float floatx4 __attribute__((ext_vector_type(4)));

typedef const __attribute__((address_space(1))) uint32_t* gptr_t;
typedef __attribute__((address_space(3))) uint32_t* lptr_t;

#define GLOAD_LDS16(gp, lp) __builtin_amdgcn_global_load_lds( \
    (gptr_t)(const void*)(gp), (lptr_t)(void*)(lp), 16, 0, 0)

// ---------------- fp32 -> fp16 convert (vectorized) ----------------
__global__ void cvt_kernel(const float* __restrict__ in, __half* __restrict__ out, long n) {
  long i = (long)blockIdx.x * blockDim.x + threadIdx.x;
  long stride = (long)gridDim.x * blockDim.x;
  for (long j = i * 4; j < n; j += stride * 4) {
    float4 v = *(const float4*)(in + j);
    __half2 a = __floats2half2_rn(v.x, v.y);
    __half2 b = __floats2half2_rn(v.z, v.w);
    uint2 p;
    p.x = *(const unsigned int*)&a;
    p.y = *(const unsigned int*)&b;
    *(uint2*)(out + j) = p;
  }
}

// ------- fp32 [E][K][N] -> fp16 [E][N][K] transpose-convert -------
__global__ void cvtT_kernel(const float* __restrict__ in, __half* __restrict__ out,
                            int K, int N) {
  __shared__ float tile[32][33];
  int e = blockIdx.z;
  const float* inp = in + (size_t)e * K * N;
  __half* outp = out + (size_t)e * K * N;
  int n0 = blockIdx.x * 32, k0 = blockIdx.y * 32;
  int tx = threadIdx.x, ty = threadIdx.y;
#pragma unroll
  for (int i = 0; i < 4; ++i)
    tile[ty + i * 8][tx] = inp[(size_t)(k0 + ty + i * 8) * N + n0 + tx];
  __syncthreads();
#pragma unroll
  for (int i = 0; i < 4; ++i)
    outp[(size_t)(n0 + ty + i * 8) * K + k0 + tx] = __float2half(tile[tx][ty + i * 8]);
}

// ---------------- router: fp32 logits, top-2, softmax ----------------
__global__ __launch_bounds__(256)
void router_kernel(const float* __restrict__ x, const float* __restrict__ Wr,
                   const float* __restrict__ br, int* __restrict__ counts,
                   int* __restrict__ sel, float* __restrict__ wTok) {
  __shared__ float wr_s[EE * DD];  // transposed [e][d], 24KB
  for (int i = threadIdx.x; i < EE * DD; i += 256) {
    int d = i >> 3, e = i & 7;
    wr_s[e * DD + d] = Wr[i];
  }
  __syncthreads();
  int wid = threadIdx.x >> 6, lane = threadIdx.x & 63;
  int t = blockIdx.x * 4 + wid;
  const float* xt = x + (size_t)t * DD;
  float acc[EE];
#pragma unroll
  for (int e = 0; e < EE; ++e) acc[e] = 0.f;
  for (int d = lane; d < DD; d += 64) {
    float xv = xt[d];
#pragma unroll
    for (int e = 0; e < EE; ++e) acc[e] += xv * wr_s[e * DD + d];
  }
#pragma unroll
  for (int off = 32; off > 0; off >>= 1)
#pragma unroll
    for (int e = 0; e < EE; ++e) acc[e] += __shfl_xor(acc[e], off);
  if (lane == 0) {
    float v[EE];
#pragma unroll
    for (int e = 0; e < EE; ++e) v[e] = acc[e] + br[e];
    int i0 = 0;
#pragma unroll
    for (int e = 1; e < EE; ++e) if (v[e] > v[i0]) i0 = e;
    int i1 = (i0 == 0) ? 1 : 0;
#pragma unroll
    for (int e = 0; e < EE; ++e) if (e != i0 && v[e] > v[i1] && e != i1) { if (v[e] > v[i1]) i1 = e; }
    float e1 = __expf(v[i1] - v[i0]);
    float s = 1.f / (1.f + e1);
    sel[2 * t] = i0; sel[2 * t + 1] = i1;
    wTok[2 * t] = s; wTok[2 * t + 1] = e1 * s;
    atomicAdd(&counts[i0], 1);
    atomicAdd(&counts[i1], 1);
  }
}

// ---------------- offsets (prefix over 8) ----------------
__global__ void offsets_kernel(const int* __restrict__ counts, int* __restrict__ offsets,
                               int* __restrict__ cursors) {
  if (threadIdx.x == 0) {
    int o = 0;
    for (int e = 0; e < EE; ++e) { offsets[e] = o; cursors[e] = o; o += counts[e]; }
  }
}

// ---------------- scatter token->slot ----------------
__global__ void scatter_kernel(const int* __restrict__ sel, int* __restrict__ cursors,
                               int* __restrict__ idxList, int* __restrict__ posTok) {
  int t = blockIdx.x * 256 + threadIdx.x;
  if (t < TK) {
#pragma unroll
    for (int k = 0; k < 2; ++k) {
      int e = sel[2 * t + k];
      int p = atomicAdd(&cursors[e], 1);
      idxList[p] = t;
      posTok[2 * t + k] = p;
    }
  }
}

// ---------------- FFN GEMM: C[cnt,N] = A[cnt,K] @ Wt[e] (+bias, gelu) ----------------
// Wt layout: [E][N][K] (pre-transposed).  A gathered via idxList (stage 1) or compacted.
// 128x128 tile, BK=64, 4 waves (2x2), 16x16x32 f16 MFMA, XOR-swizzled LDS.
template<int KD, int ND, bool GATHER, bool GELU>
__global__ __launch_bounds__(256)
void ffn_gemm(const __half* __restrict__ A, const __half* __restrict__ Wt,
              const float* __restrict__ Bias, __half* __restrict__ Out,
              const int* __restrict__ counts, const int* __restrict__ offsets,
              const int* __restrict__ idxList) {
  const int e = blockIdx.z;
  const int cnt = counts[e];
  const int m0 = blockIdx.y * 128;
  if (cnt == 0 || m0 >= cnt) return;
  const int off = offsets[e];
  const int n0 = blockIdx.x * 128;
  const __half* We = Wt + (size_t)e * KD * ND;
  const float* be = Bias + (size_t)e * ND;

  __shared__ __align__(16) __half As[128 * 64];
  __shared__ __align__(16) __half Bs[128 * 64];

  const int tid = threadIdx.x;

  // staging source addresses: slot s = i*256+tid; row = s/8, scol = s%8
  // global col pre-swizzled: (scol ^ (row&7))*8  (matches swizzled read below)
  const __half* abase[4];
  const __half* bbase[4];
#pragma unroll
  for (int i = 0; i < 4; ++i) {
    int s = i * 256 + tid;
    int row = s >> 3;
    int sc = s & 7;
    int r = m0 + row; if (r > cnt - 1) r = cnt - 1;  // clamp tail (writes guarded)
    size_t arow = GATHER ? (size_t)idxList[off + r] : (size_t)(off + r);
    abase[i] = A + arow * KD + ((sc ^ (row & 7)) << 3);
    bbase[i] = We + (size_t)(n0 + row) * KD + ((sc ^ (row & 7)) << 3);
  }

  floatx4 acc[4][4];
#pragma unroll
  for (int mi = 0; mi < 4; ++mi)
#pragma unroll
    for (int ni = 0; ni < 4; ++ni) acc[mi][ni] = (floatx4){0.f, 0.f, 0.f, 0.f};

  const int lane = tid & 63;
  const int wv = tid >> 6;
  const int wr = wv >> 1, wc = wv & 1;
  const int lrow = lane & 15, lg = lane >> 4;

  int aoff[4][2], boff[4][2];
#pragma unroll
  for (int mi = 0; mi < 4; ++mi) {
    int row = wr * 64 + mi * 16 + lrow;
#pragma unroll
    for (int kk = 0; kk < 2; ++kk) {
      int slot = kk * 4 + lg;
      aoff[mi][kk] = row * 64 + ((slot ^ (row & 7)) << 3);
    }
  }
#pragma unroll
  for (int ni = 0; ni < 4; ++ni) {
    int row = wc * 64 + ni * 16 + lrow;
#pragma unroll
    for (int kk = 0; kk < 2; ++kk) {
      int slot = kk * 4 + lg;
      boff[ni][kk] = row * 64 + ((slot ^ (row & 7)) << 3);
    }
  }

  for (int k0 = 0; k0 < KD; k0 += 64) {
    __syncthreads();  // previous tile fully consumed
#pragma unroll
    for (int i = 0; i < 4; ++i)
      GLOAD_LDS16(abase[i] + k0, &As[i * 2048 + tid * 8]);
#pragma unroll
    for (int i = 0; i < 4; ++i)
      GLOAD_LDS16(bbase[i] + k0, &Bs[i * 2048 + tid * 8]);
    __syncthreads();  // compiler drains vmcnt before barrier
#pragma unroll
    for (int kk = 0; kk < 2; ++kk) {
      half8 af[4], bf[4];
#pragma unroll
      for (int mi = 0; mi < 4; ++mi) af[mi] = *(const half8*)&As[aoff[mi][kk]];
#pragma unroll
      for (int ni = 0; ni < 4; ++ni) bf[ni] = *(const half8*)&Bs[boff[ni][kk]];
#pragma unroll
      for (int mi = 0; mi < 4; ++mi)
#pragma unroll
        for (int ni = 0; ni < 4; ++ni)
          acc[mi][ni] = __builtin_amdgcn_mfma_f32_16x16x32_f16(af[mi], bf[ni], acc[mi][ni], 0, 0, 0);
    }
  }

  // epilogue: C row = (lane>>4)*4 + j, col = lane&15 per 16x16 fragment
#pragma unroll
  for (int ni = 0; ni < 4; ++ni) {
    int col = n0 + wc * 64 + ni * 16 + lrow;
    float bv = be[col];
#pragma unroll
    for (int mi = 0; mi < 4; ++mi) {
      int rbase = m0 + wr * 64 + mi * 16 + lg * 4;
#pragma unroll
      for (int j = 0; j < 4; ++j) {
        int r = rbase + j;
        if (r < cnt) {
          float v = acc[mi][ni][j] + bv;
          if (GELU) v = 0.5f * v * (1.f + erff(v * 0.70710678118654752f));
          Out[(size_t)(off + r) * ND + col] = __float2half(v);
        }
      }
    }
  }
}

// ---------------- combine: out[t] = w0*yc[p0] + w1*yc[p1] ----------------
__global__ void combine_kernel(const __half* __restrict__ yc, const float* __restrict__ wTok,
                               const int* __restrict__ posTok, float* __restrict__ out) {
  int t = blockIdx.x;
  int d = threadIdx.x * 4;
  if (d >= DD) return;
  float w0 = wTok[2 * t], w1 = wTok[2 * t + 1];
  const __half2* a = (const __half2*)(yc + (size_t)posTok[2 * t] * DD + d);
  const __half2* b = (const __half2*)(yc + (size_t)posTok[2 * t + 1] * DD + d);
  float2 a0 = __half22float2(a[0]), a1 = __half22float2(a[1]);
  float2 b0 = __half22float2(b[0]), b1 = __half22float2(b[1]);
  float4 r;
  r.x = w0 * a0.x + w1 * b0.x;
  r.y = w0 * a0.y + w1 * b0.y;
  r.z = w0 * a1.x + w1 * b1.x;
  r.w = w0 * a1.y + w1 * b1.y;
  *(float4*)(out + (size_t)t * DD + d) = r;
}

extern "C" void kernel_launch(void* const* d_in, const int* in_sizes, int n_in,
                              void* d_out, int out_size, void* d_ws, size_t ws_size,
                              hipStream_t stream) {
  const float* x  = (const float*)d_in[0];
  const float* Wr = (const float*)d_in[1];
  const float* br = (const float*)d_in[2];
  const float* W1 = (const float*)d_in[3];
  const float* b1 = (const float*)d_in[4];
  const float* W2 = (const float*)d_in[5];
  const float* b2 = (const float*)d_in[6];
  const float* W3 = (const float*)d_in[7];
  const float* b3 = (const float*)d_in[8];
  float* out = (float*)d_out;

  char* ws = (char*)d_ws;
  size_t o = 0;
  auto alloc = [&](size_t bytes) {
    char* p = ws + o;
    o += (bytes + 255) & ~(size_t)255;
    return p;
  };
  __half* xh   = (__half*)alloc((size_t)TK * DD * 2);
  __half* w1t  = (__half*)alloc((size_t)EE * DD * II * 2);
  __half* w2t  = (__half*)alloc((size_t)EE * II * HH * 2);
  __half* w3t  = (__half*)alloc((size_t)EE * HH * DD * 2);
  __half* h1   = (__half*)alloc((size_t)2 * TK * II * 2);
  __half* h2   = (__half*)alloc((size_t)2 * TK * HH * 2);
  __half* yc   = (__half*)alloc((size_t)2 * TK * DD * 2);
  int*   idxL  = (int*)alloc(2 * TK * 4);
  int*   sel   = (int*)alloc(2 * TK * 4);
  float* wTok  = (float*)alloc(2 * TK * 4);
  int*   posT  = (int*)alloc(2 * TK * 4);
  int*   counts  = (int*)alloc(256);
  int*   offsets = (int*)alloc(256);
  int*   cursors = (int*)alloc(256);
  if (o > ws_size) return;  // workspace too small -> loud absmax failure

  hipMemsetAsync(counts, 0, 256, stream);

  cvt_kernel<<<2048, 256, 0, stream>>>(x, xh, (long)TK * DD);
  cvtT_kernel<<<dim3(II / 32, DD / 32, EE), dim3(32, 8), 0, stream>>>(W1, w1t, DD, II);
  cvtT_kernel<<<dim3(HH / 32, II / 32, EE), dim3(32, 8), 0, stream>>>(W2, w2t, II, HH);
  cvtT_kernel<<<dim3(DD / 32, HH / 32, EE), dim3(32, 8), 0, stream>>>(W3, w3t, HH, DD);
  router_kernel<<<TK / 4, 256, 0, stream>>>(x, Wr, br, counts, sel, wTok);
  offsets_kernel<<<1, 64, 0, stream>>>(counts, offsets, cursors);
  scatter_kernel<<<TK / 256, 256, 0, stream>>>(sel, cursors, idxL, posT);

  ffn_gemm<DD, II, true, true><<<dim3(II / 128, 128, EE), 256, 0, stream>>>(
      xh, w1t, b1, h1, counts, offsets, idxL);
  ffn_gemm<II, HH, false, true><<<dim3(HH / 128, 128, EE), 256, 0, stream>>>(
      h1, w2t, b2, h2, counts, offsets, idxL);
  ffn_gemm<HH, DD, false, false><<<dim3(DD / 128, 128, EE), 256, 0, stream>>>(
      h2, w3t, b3, yc, counts, offsets, idxL);

  combine_kernel<<<TK, 192, 0, stream>>>(yc, wTok, posT, out);
}